// Round 10
// baseline (1514.094 us; speedup 1.0000x reference)
//
#include <hip/hip_runtime.h>
#include <math.h>

#define KD    1024   // k
#define BATCH 2048
#define XD    784
#define YD    10

typedef _Float16 f16;
typedef _Float16 f16x8 __attribute__((ext_vector_type(8)));
typedef _Float16 f16x4 __attribute__((ext_vector_type(4)));
typedef float    f32x4 __attribute__((ext_vector_type(4)));

// ---------------------------------------------------------------------------
// async global->LDS, 16B per lane: per-lane global src, wave-uniform LDS dest;
// lane l lands at dst + 16*l.
// ---------------------------------------------------------------------------
__device__ __forceinline__ void gll16(const void* g, void* l)
{
    __builtin_amdgcn_global_load_lds(
        (const __attribute__((address_space(1))) void*)g,
        (__attribute__((address_space(3))) void*)l,
        16, 0, 0);
}

#define TS  64
#define KS  32
#define LDP 68

// ---------------------------------------------------------------------------
// atb tile body: C[i][j] = sum_d A[d][i]*B[d][j]  (A:[K x M], B:[K x N])
// ---------------------------------------------------------------------------
__device__ __forceinline__ void atb_body(const float* __restrict__ A,
                                         const float* __restrict__ B,
                                         float* __restrict__ C,
                                         int M, int N, int K, int bx, int by,
                                         float (*As)[LDP], float (*Bs)[LDP])
{
    const int tid = threadIdx.x;
    const int tx = tid & 15, ty = tid >> 4;
    const int i0 = by * TS, j0 = bx * TS;
    float acc[4][4] = {};

    for (int k0 = 0; k0 < K; k0 += KS) {
#pragma unroll
        for (int q = 0; q < 2; ++q) {
            const int f  = tid + q * 256;
            const int kr = f >> 4;
            const int cc = (f & 15) << 2;
            float4 av = make_float4(0.f, 0.f, 0.f, 0.f);
            float4 bv = av;
            if (k0 + kr < K) {
                av = *(const float4*)(A + (size_t)(k0 + kr) * M + i0 + cc);
                bv = *(const float4*)(B + (size_t)(k0 + kr) * N + j0 + cc);
            }
            *(float4*)&As[kr][cc] = av;
            *(float4*)&Bs[kr][cc] = bv;
        }
        __syncthreads();
#pragma unroll
        for (int kk = 0; kk < KS; ++kk) {
            const float4 a4 = *(const float4*)&As[kk][ty << 2];
            const float4 b4 = *(const float4*)&Bs[kk][tx << 2];
            const float a[4] = {a4.x, a4.y, a4.z, a4.w};
            const float b[4] = {b4.x, b4.y, b4.z, b4.w};
#pragma unroll
            for (int r = 0; r < 4; ++r)
#pragma unroll
                for (int c = 0; c < 4; ++c)
                    acc[r][c] = fmaf(a[r], b[c], acc[r][c]);
        }
        __syncthreads();
    }
#pragma unroll
    for (int r = 0; r < 4; ++r) {
        float4 o = make_float4(acc[r][0], acc[r][1], acc[r][2], acc[r][3]);
        *(float4*)(C + (size_t)(i0 + (ty << 2) + r) * N + j0 + (tx << 2)) = o;
    }
}

// ---------------------------------------------------------------------------
// Fused setup (one launch): blocks [0,256) WtW = Wx^T Wx; [256,768) XtW = x^T Wx;
// [768,1792) h_init -> f16; block 1792: power-iteration init vector.
// ---------------------------------------------------------------------------
__global__ __launch_bounds__(256) void setup_fused(const float* __restrict__ x,
                                                   const float* __restrict__ Wx,
                                                   const float* __restrict__ h_init,
                                                   float* __restrict__ WtW,
                                                   float* __restrict__ XtW,
                                                   f16* __restrict__ h0f,
                                                   float* __restrict__ w0)
{
    __shared__ float As[KS][LDP];
    __shared__ float Bs[KS][LDP];
    const int blk = blockIdx.x;
    if (blk < 256) {
        atb_body(Wx, Wx, WtW, KD, KD, XD, blk & 15, blk >> 4, As, Bs);
    } else if (blk < 768) {
        const int l = blk - 256;
        atb_body(x, Wx, XtW, BATCH, KD, XD, l & 15, l >> 4, As, Bs);
    } else if (blk < 1792) {
        const int i = (blk - 768) * 256 + threadIdx.x;     // x8 groups, 262144 total
        const f32x4 a = ((const f32x4*)h_init)[2 * i];
        const f32x4 b = ((const f32x4*)h_init)[2 * i + 1];
        f16x8 o;
#pragma unroll
        for (int j = 0; j < 4; ++j) { o[j] = (f16)a[j]; o[j + 4] = (f16)b[j]; }
        ((f16x8*)h0f)[i] = o;
    } else {
        ((float4*)w0)[threadIdx.x] = make_float4(0.03125f, 0.03125f, 0.03125f, 0.03125f);
    }
}

// ---------------------------------------------------------------------------
// Fused convert (one launch): blocks [0,512): bhi = f16(256*WtW);
// blocks [512,2560): XtW -> f16 hi/lo planes.
// ---------------------------------------------------------------------------
__global__ __launch_bounds__(256) void convert_fused(const float* __restrict__ WtW,
                                                     const float* __restrict__ XtW,
                                                     f16* __restrict__ bhi,
                                                     f16* __restrict__ xth,
                                                     f16* __restrict__ xtl)
{
    const int blk = blockIdx.x;
    if (blk < 512) {
        const int i = blk * 256 + threadIdx.x;             // x8, 131072 total
        const f32x4 a = ((const f32x4*)WtW)[2 * i];
        const f32x4 b = ((const f32x4*)WtW)[2 * i + 1];
        f16x8 o;
#pragma unroll
        for (int j = 0; j < 4; ++j) {
            o[j]     = (f16)(256.0f * a[j]);
            o[j + 4] = (f16)(256.0f * b[j]);
        }
        ((f16x8*)bhi)[i] = o;
    } else {
        const int i = (blk - 512) * 256 + threadIdx.x;     // x4, 524288 total
        const float4 v = ((const float4*)XtW)[i];
        const f16 h0 = (f16)v.x, h1 = (f16)v.y, h2 = (f16)v.z, h3 = (f16)v.w;
        f16x4 hv = {h0, h1, h2, h3};
        f16x4 lv = {(f16)(v.x - (float)h0), (f16)(v.y - (float)h1),
                    (f16)(v.z - (float)h2), (f16)(v.w - (float)h3)};
        ((f16x4*)xth)[i] = hv;
        ((f16x4*)xtl)[i] = lv;
    }
}

// ---------------------------------------------------------------------------
// Fused FISTA step, single-pass f16 MFMA, BARRIER-FREE main loop:
//   acc = Y @ f16(256*WtW) ; grad = acc/256 - XtW(f16 hi+lo)
//   Hout = max(Y - grad*invL, 0); Yout = Hout + cm*(Hout - Hin)
// BM=128, BN=32: the block's ENTIRE B n-panel (32 cols x 1024 k, 64 KiB) is
// staged into LDS once in the prologue (one barrier). Main loop: A fragments
// direct global->VGPR (2-deep reg lookahead, L2-resident), B fragments
// ds_read from resident panel (chunk-major, conflict-free), 0 barriers.
// 256 thr = 4 waves (4m x 1n), wave-tile 32x32. Grid 32x16 = 512 blocks =
// 2 blocks/CU (128 KiB LDS), 2 waves/SIMD. XCD swizzle: 4m x 16n per XCD.
// Accumulation order over k (kt, s, single pass) identical to round 9 ->
// bit-identical output.
// ---------------------------------------------------------------------------
#define BMF 128
#define BNF 32

__global__ __launch_bounds__(256, 2) void fista10(
    const f16* __restrict__ yhP,   // A operand + epilogue y  [BATCH][KD]
    const f16* __restrict__ hhP,   // epilogue h              [BATCH][KD]
    const f16* __restrict__ bhiP,  // f16(256*WtW)            [KD][KD]
    const f16* __restrict__ xthP,  // XtW hi plane (f16)      [BATCH][KD]
    const f16* __restrict__ xtlP,  // XtW lo plane (f16)
    const float* __restrict__ invLp, float cm,
    f16* __restrict__ HO, f16* __restrict__ YO)
{
    __shared__ char lds[65536];    // B panel: 64 chunks x 1 KiB; epilogue reuses

    const int t    = threadIdx.x;
    const int lane = t & 63;
    const int wid  = t >> 6;       // 0..3 = m-wave
    const int lr   = lane & 15;
    const int lk   = (lane >> 4) * 8;

    // XCD swizzle: per-XCD region = 4 m-panels x 16 n-panels (~2MB < 4MB L2)
    const int bid = blockIdx.y * gridDim.x + blockIdx.x;   // 0..511
    const int xc  = bid & 7, j = bid >> 3;                 // j: 0..63
    const int mi  = (xc >> 1) * 4 + (j >> 4);              // 0..15
    const int ni  = (xc & 1) * 16 + (j & 15);              // 0..31
    const int m0  = mi * BMF, n0 = ni * BNF;

    // ---- prologue: stage whole B panel (64 chunks of 1 KiB; 16 per wave) ----
    // chunk c: kt=c>>2, s=(c>>1)&1, b=c&1; lane l -> col n0+16b+(l&15),
    //          k = kt*64 + s*32 + 8*(l>>4); LDS dest c*1024 + 16*l.
#pragma unroll
    for (int i = 0; i < 16; ++i) {
        const int c = wid * 16 + i;
        const int b = c & 1, s = (c >> 1) & 1, kt = c >> 2;
        gll16(bhiP + (size_t)(n0 + 16 * b + lr) * KD + kt * 64 + s * 32 + lk,
              lds + c * 1024 + lane * 16);
    }

    // A row bases for this wave (2 x 16-row frags), k-lane folded in
    const f16* aP[2];
#pragma unroll
    for (int f = 0; f < 2; ++f)
        aP[f] = yhP + (size_t)(m0 + wid * 32 + 16 * f + lr) * KD + lk;

    // preload A k-tiles 0,1 (overlaps B staging)
    f16x8 Abuf[3][2][2];           // [slot][s][f]
#pragma unroll
    for (int kt = 0; kt < 2; ++kt)
#pragma unroll
        for (int s = 0; s < 2; ++s)
#pragma unroll
            for (int f = 0; f < 2; ++f)
                Abuf[kt][s][f] = *(const f16x8*)(aP[f] + kt * 64 + 32 * s);

    asm volatile("s_waitcnt vmcnt(0)" ::: "memory");   // B panel landed
    __builtin_amdgcn_s_barrier();
    asm volatile("" ::: "memory");

    f32x4 acc[2][2] = {};

    // ---- main loop: NO barriers, no LDS writes ----
#pragma unroll
    for (int kt = 0; kt < 16; ++kt) {
        const int cur = kt % 3, nx = (kt + 2) % 3;
        if (kt < 14) {
#pragma unroll
            for (int s = 0; s < 2; ++s)
#pragma unroll
                for (int f = 0; f < 2; ++f)
                    Abuf[nx][s][f] = *(const f16x8*)(aP[f] + (kt + 2) * 64 + 32 * s);
        }
#pragma unroll
        for (int s = 0; s < 2; ++s) {
            const f16x8 B0 = *(const f16x8*)(lds + (kt * 4 + s * 2 + 0) * 1024 + lane * 16);
            const f16x8 B1 = *(const f16x8*)(lds + (kt * 4 + s * 2 + 1) * 1024 + lane * 16);
#pragma unroll
            for (int f = 0; f < 2; ++f) {
                acc[f][0] = __builtin_amdgcn_mfma_f32_16x16x32_f16(Abuf[cur][s][f], B0, acc[f][0], 0, 0, 0);
                acc[f][1] = __builtin_amdgcn_mfma_f32_16x16x32_f16(Abuf[cur][s][f], B1, acc[f][1], 0, 0, 0);
            }
        }
    }

    // ---- epilogue: acc -> LDS fp32 [128][36] -> linear global I/O ----
    __syncthreads();               // all B reads done before overwrite
    float* eb = (float*)lds;
#pragma unroll
    for (int f = 0; f < 2; ++f)
#pragma unroll
        for (int b = 0; b < 2; ++b) {
            const int r0 = wid * 32 + 16 * f + 4 * (lane >> 4);
            const int cl = 16 * b + lr;
#pragma unroll
            for (int r = 0; r < 4; ++r)
                eb[(r0 + r) * 36 + cl] = acc[f][b][r];
        }
    __syncthreads();

    const int row = t >> 1;            // 0..127
    const int cb  = (t & 1) * 16;      // 0 / 16
    const float invL  = invLp[0];
    const float invLs = invL * 0.00390625f;   // invL/256 (fold WtW scale)
    const size_t gb = (size_t)(m0 + row) * KD + n0 + cb;
#pragma unroll
    for (int q = 0; q < 2; ++q) {
        const f32x4 a0 = *(const f32x4*)(eb + row * 36 + cb + q * 8);
        const f32x4 a1 = *(const f32x4*)(eb + row * 36 + cb + q * 8 + 4);
        const size_t g8 = gb + q * 8;
        const f16x8 yh8 = *(const f16x8*)(yhP + g8);
        const f16x8 hh8 = *(const f16x8*)(hhP + g8);
        const f16x8 xh8 = *(const f16x8*)(xthP + g8);
        const f16x8 xl8 = *(const f16x8*)(xtlP + g8);
        f16x8 oh, oy;
#pragma unroll
        for (int jj = 0; jj < 8; ++jj) {
            const float av = (jj < 4) ? a0[jj] : a1[jj - 4];
            const float xv = (float)xh8[jj] + (float)xl8[jj];
            const float yv = (float)yh8[jj];
            const float hv = (float)hh8[jj];
            const float t1 = fmaf(invL, xv, yv);
            const float hn = fmaxf(fmaf(-invLs, av, t1), 0.f);
            const float yn = fmaf(cm, hn - hv, hn);
            oh[jj] = (f16)hn;
            oy[jj] = (f16)yn;
        }
        *(f16x8*)(HO + g8) = oh;
        *(f16x8*)(YO + g8) = oy;
    }
}

// ---------------------------------------------------------------------------
// Power iteration (deterministic, no atomics): wout = WtW @ (win/||win||)
// ---------------------------------------------------------------------------
__global__ __launch_bounds__(256) void matvec_n_kernel(const float* __restrict__ WtW,
                                                       const float* __restrict__ win,
                                                       float* __restrict__ wout)
{
    __shared__ float red[4];
    __shared__ float invnS;
    const int t = threadIdx.x;
    const int wave = t >> 6, lane = t & 63;

    const float4 wv = *(const float4*)(win + t * 4);
    float ss = wv.x * wv.x + wv.y * wv.y + wv.z * wv.z + wv.w * wv.w;
#pragma unroll
    for (int off = 32; off > 0; off >>= 1) ss += __shfl_down(ss, off);
    if (lane == 0) red[wave] = ss;
    __syncthreads();
    if (t == 0) invnS = 1.0f / (sqrtf(red[0] + red[1] + red[2] + red[3]) + 1e-12f);
    __syncthreads();
    const float invn = invnS;

    const int row = blockIdx.x * 4 + wave;
    const float* rp = WtW + (size_t)row * KD;
    float s = 0.f;
#pragma unroll
    for (int q = 0; q < KD / 64; ++q)
        s = fmaf(rp[lane + 64 * q], win[lane + 64 * q] * invn, s);
#pragma unroll
    for (int off = 32; off > 0; off >>= 1) s += __shfl_down(s, off);
    if (lane == 0) wout[row] = s;
}

__global__ __launch_bounds__(1024) void rayleigh_n_kernel(const float* __restrict__ wprev,
                                                          const float* __restrict__ wlast,
                                                          float* __restrict__ invL)
{
    __shared__ float red[16];
    __shared__ float invnS;
    const int t = threadIdx.x;
    const float a = wprev[t];
    float ss = a * a;
#pragma unroll
    for (int off = 32; off > 0; off >>= 1) ss += __shfl_down(ss, off);
    if ((t & 63) == 0) red[t >> 6] = ss;
    __syncthreads();
    if (t < 64) {
        float v = (t < 16) ? red[t] : 0.f;
#pragma unroll
        for (int off = 8; off > 0; off >>= 1) v += __shfl_down(v, off);
        if (t == 0) invnS = 1.0f / (sqrtf(v) + 1e-12f);
    }
    __syncthreads();
    float s = (a * invnS) * wlast[t];
#pragma unroll
    for (int off = 32; off > 0; off >>= 1) s += __shfl_down(s, off);
    __syncthreads();
    if ((t & 63) == 0) red[t >> 6] = s;
    __syncthreads();
    if (t == 0) {
        float tot = 0.f;
#pragma unroll
        for (int i = 0; i < 16; ++i) tot += red[i];
        invL[0] = 1.0f / tot;
    }
}

// ---------------------------------------------------------------------------
// out[i][b] = sum_j Wy[i][j] * H[b][j]   (out: [YD x BATCH])
// ---------------------------------------------------------------------------
__global__ __launch_bounds__(256) void ypred_kernel(const float* __restrict__ Wy,
                                                    const f16* __restrict__ hh,
                                                    float* __restrict__ out)
{
    const int wave = threadIdx.x >> 6;
    const int lane = threadIdx.x & 63;
    const int b    = blockIdx.x * 4 + wave;
    float p[YD] = {};
    const f16* hp = hh + (size_t)b * KD;
#pragma unroll 4
    for (int q = 0; q < KD / 64; ++q) {
        const int j = lane + 64 * q;
        const float hv = (float)hp[j];
#pragma unroll
        for (int i = 0; i < YD; ++i)
            p[i] = fmaf(Wy[i * KD + j], hv, p[i]);
    }
#pragma unroll
    for (int i = 0; i < YD; ++i) {
        float s = p[i];
#pragma unroll
        for (int off = 32; off > 0; off >>= 1)
            s += __shfl_down(s, off);
        if (lane == 0) out[(size_t)i * BATCH + b] = s;
    }
}

// ---------------------------------------------------------------------------
extern "C" void kernel_launch(void* const* d_in, const int* in_sizes, int n_in,
                              void* d_out, int out_size, void* d_ws, size_t ws_size,
                              hipStream_t stream)
{
    const float* x      = (const float*)d_in[0];   // [784 x 2048]
    const float* Wx     = (const float*)d_in[1];   // [784 x 1024]
    const float* Wy     = (const float*)d_in[2];   // [10 x 1024]
    const float* h_init = (const float*)d_in[3];   // [2048 x 1024]
    float* out = (float*)d_out;                    // [10 x 2048]

    char* base = (char*)d_ws;
    const size_t MB = 1 << 20;
    float* WtW  = (float*)(base + 0 * MB);         // 4 MB
    float* XtW  = (float*)(base + 4 * MB);         // 8 MB
    f16* bhiP   = (f16*)(base + 12 * MB);          // 2 MB
    f16* xthP   = (f16*)(base + 14 * MB);          // 4 MB
    f16* xtlP   = (f16*)(base + 18 * MB);          // 4 MB
    f16* h0f    = (f16*)(base + 22 * MB);          // 4 MB
    f16* hA     = (f16*)(base + 26 * MB);
    f16* yA     = (f16*)(base + 30 * MB);
    f16* hB     = (f16*)(base + 34 * MB);
    f16* yB     = (f16*)(base + 38 * MB);
    float* wA   = (float*)(base + 42 * MB);
    float* wB   = (float*)(base + 42 * MB + 8192);
    float* invL = (float*)(base + 42 * MB + 16384);

    // 1) fused setup: WtW, XtW, h_init->f16, power-init   (one launch)
    setup_fused<<<1793, 256, 0, stream>>>(x, Wx, h_init, WtW, XtW, h0f, wA);

    // 2) fused convert: bhi = f16(256*WtW); XtW -> f16 hi/lo
    convert_fused<<<2560, 256, 0, stream>>>(WtW, XtW, bhiP, xthP, xtlP);

    // 3) Lipschitz via power iteration (spectrum ~rank-1 dominant; 11 matvecs
    //    reach fp32 convergence). writes: it even -> wB, odd -> wA;
    //    it=9 -> wA(u10), it=10 -> wB(u11).
    float* wcur = wA; float* wnxt = wB;
    for (int it = 0; it < 11; ++it) {
        matvec_n_kernel<<<KD / 4, 256, 0, stream>>>(WtW, wcur, wnxt);
        float* tmp = wcur; wcur = wnxt; wnxt = tmp;
    }
    rayleigh_n_kernel<<<1, 1024, 0, stream>>>(wA, wB, invL);  // (u10, u11)

    // 4) 60 FISTA iterations (t restarts at iter 50: y = h, t = 1)
    float t = 1.0f;
    const f16 *yin = h0f, *hin = h0f;
    int outSel = 1;                                 // 1 -> A set, 0 -> B set
    for (int n = 0; n < 60; ++n) {
        if (n == 50) { t = 1.0f; yin = hin; }
        const float tn = 0.5f * (1.0f + sqrtf(1.0f + 4.0f * t * t));
        const float cm = (t - 1.0f) / tn;
        f16* ho = outSel ? hA : hB;
        f16* yo = outSel ? yA : yB;
        fista10<<<dim3(32, 16), 256, 0, stream>>>(
            yin, hin, bhiP, xthP, xtlP, invL, cm, ho, yo);
        t = tn;
        hin = ho; yin = yo;
        outSel ^= 1;
    }

    // 5) out = Wy @ h^T
    ypred_kernel<<<BATCH / 4, 256, 0, stream>>>(Wy, hin, out);
}